// Round 6
// baseline (492.009 us; speedup 1.0000x reference)
//
#include <hip/hip_runtime.h>
#include <hip/hip_bf16.h>

#define D_DIM 2048
#define E_DIM 8

typedef __attribute__((ext_vector_type(8))) short short8;
typedef __attribute__((ext_vector_type(4))) float f32x4;

__device__ __forceinline__ unsigned short f2bf(float f) {
  union { float f; unsigned int u; } v; v.f = f;
  unsigned int u = v.u;
  u += 0x7FFFu + ((u >> 16) & 1u);   // round-to-nearest-even
  return (unsigned short)(u >> 16);
}

__device__ __forceinline__ void async_copy16(const void* g, void* l) {
  __builtin_amdgcn_global_load_lds((const __attribute__((address_space(1))) void*)g,
                                   (__attribute__((address_space(3))) void*)l,
                                   16, 0, 0);
}

// ---------------- f32 -> bf16 convert into strided (concatenated) dest ----------------
__global__ void k_cvt_bf16s(const float* __restrict__ in,
                            unsigned short* __restrict__ out,
                            int rows, int cols, int out_ld) {
  const int cpr = cols >> 3;   // short8 chunks per row
  long long i = (long long)blockIdx.x * blockDim.x + threadIdx.x;
  const long long total = (long long)rows * cpr;
  const long long stride = (long long)gridDim.x * blockDim.x;
  for (; i < total; i += stride) {
    const int r = (int)(i / cpr);
    const int c8 = (int)(i % cpr);
    const float* src = in + (size_t)r * cols + c8 * 8;
    float4 a = *(const float4*)(src);
    float4 b = *(const float4*)(src + 4);
    short8 rr;
    rr[0] = (short)f2bf(a.x); rr[1] = (short)f2bf(a.y);
    rr[2] = (short)f2bf(a.z); rr[3] = (short)f2bf(a.w);
    rr[4] = (short)f2bf(b.x); rr[5] = (short)f2bf(b.y);
    rr[6] = (short)f2bf(b.z); rr[7] = (short)f2bf(b.w);
    *(short8*)(out + (size_t)r * out_ld + c8 * 8) = rr;
  }
}

// ---------------- transpose f32 -> bf16 (zero pad), strided out ----------------
__global__ void k_transpose_bf16(const float* __restrict__ in, int in_rows, int in_cols,
                                 int in_ld, unsigned short* __restrict__ out,
                                 int out_rows, int out_ld) {
  __shared__ float tile[32][33];
  const int tx = threadIdx.x;  // 0..31
  const int ty = threadIdx.y;  // 0..7
  const int c = blockIdx.x * 32 + tx;
  #pragma unroll
  for (int i = 0; i < 4; ++i) {
    const int r = blockIdx.y * 32 + ty + i * 8;
    float vv = 0.0f;
    if (r < in_rows && c < in_cols) vv = in[(size_t)r * in_ld + c];
    tile[ty + i * 8][tx] = vv;
  }
  __syncthreads();
  const int oc = blockIdx.y * 32 + tx;   // = original row
  #pragma unroll
  for (int i = 0; i < 4; ++i) {
    const int orow = blockIdx.x * 32 + ty + i * 8;  // = original col (padded)
    if (orow < out_rows && oc < in_rows)
      out[(size_t)orow * out_ld + oc] = f2bf(tile[tx][ty + i * 8]);
  }
}

// ---------------- pad-copy f32 -> bf16, strided out ----------------
__global__ void k_pad_bf16(const float* __restrict__ in, unsigned short* __restrict__ out,
                           int rows, int cols, int cols_pad, int out_ld) {
  long long idx = (long long)blockIdx.x * blockDim.x + threadIdx.x;
  const long long total = (long long)rows * cols_pad;
  const long long stride = (long long)gridDim.x * blockDim.x;
  for (; idx < total; idx += stride) {
    const int r = (int)(idx / cols_pad);
    const int c = (int)(idx % cols_pad);
    out[(size_t)r * out_ld + c] = (c < cols) ? f2bf(in[(size_t)r * cols + c])
                                             : (unsigned short)0;
  }
}

// ---------------- routing: writes A2-part of Acat ----------------
__global__ void k_route(const float* __restrict__ xu, int k, int k_pad,
                        const float* __restrict__ Wg1, const float* __restrict__ Wg2,
                        const float* __restrict__ lam,  // [E][k]
                        unsigned short* __restrict__ Acat, int acat_ld,
                        float* __restrict__ rowscale, int Nrows) {
  const int w = threadIdx.x >> 6;
  const int lane = threadIdx.x & 63;
  const int row = blockIdx.x * 4 + w;
  if (row >= Nrows) return;
  const float* xr = xu + (size_t)row * k_pad;
  float s = 0.0f;
  for (int kk = lane; kk < k; kk += 64) s += xr[kk] * Wg1[kk];
  #pragma unroll
  for (int off = 32; off; off >>= 1) s += __shfl_xor(s, off);
  float lg[E_DIM];
  float mx = -INFINITY;
  #pragma unroll
  for (int e = 0; e < E_DIM; ++e) { lg[e] = s * Wg2[e]; mx = fmaxf(mx, lg[e]); }
  float Z = 0.0f;
  #pragma unroll
  for (int e = 0; e < E_DIM; ++e) { lg[e] = expf(lg[e] - mx); Z += lg[e]; }
  float g[E_DIM]; float gsum = 0.0f;
  #pragma unroll
  for (int e = 0; e < E_DIM; ++e) { g[e] = lg[e] / Z; gsum += g[e]; }
  const float inv = 1.0f / gsum;
  if (lane == 0) rowscale[row] = gsum;
  unsigned short* arow = Acat + (size_t)row * acat_ld + D_DIM;
  for (int kk = lane; kk < k_pad; kk += 64) {
    if (kk < k) {
      float c = 0.0f;
      #pragma unroll
      for (int e = 0; e < E_DIM; ++e) c += g[e] * lam[(size_t)e * k + kk];
      arow[kk] = f2bf(xr[kk] * (c * inv));
    } else {
      arow[kk] = 0;
    }
  }
}

// ---------------- 128x128 GEMM: slot-interleaved LDS, hoisted addrs, x4 unroll ------
// LDS layout: A chunks 0..7 (16 rows each) at c*4096 + S*1024; B at +32768.
// Body tt: stage(tt+3) -> ds_read frags(tt+1) into alt set -> 16 MFMA(tt) ->
// vmcnt(4) -> barrier.  Swizzle: 16B slot j of row r at j ^ ((r>>1)&3).
__global__ __launch_bounds__(256, 2) void k_gemm128(
    const unsigned short* __restrict__ A, int lda,
    const unsigned short* __restrict__ B, int ldb,
    int Ktot, float* __restrict__ Cout, int ldc) {
  __shared__ unsigned short lds[32768];   // 64 KiB
  char* ldsc = (char*)lds;
  const int tid = threadIdx.x;
  const int lane = tid & 63;
  const int w = tid >> 6;            // 0..3
  const long long brow = (long long)blockIdx.x * 128;
  const long long bcol = (long long)blockIdx.y * 128;
  const int c0 = w * 2;
  const int sr0 = lane >> 2, sj = lane & 3;
  const int l15 = lane & 15, jhi = lane >> 4;
  const int jx = jhi ^ ((l15 >> 1) & 3);
  const int sjx = sj ^ ((sr0 >> 1) & 3);
  const int wr = (w >> 1) * 64;
  const int wc = (w & 1) * 64;

  int preA[4], preB[4];
  #pragma unroll
  for (int m = 0; m < 4; ++m) preA[m] = ((w >> 1) * 4 + m) * 4096 + l15 * 64 + jx * 16;
  #pragma unroll
  for (int n = 0; n < 4; ++n) preB[n] = 32768 + ((w & 1) * 4 + n) * 4096 + l15 * 64 + jx * 16;

  const char* gA[2]; const char* gB[2]; char* dA[2]; char* dB[2];
  #pragma unroll
  for (int cc = 0; cc < 2; ++cc) {
    const int ch = c0 + cc;
    gA[cc] = (const char*)A + ((brow + ch * 16 + sr0) * (long long)lda + sjx * 8) * 2;
    gB[cc] = (const char*)B + ((bcol + ch * 16 + sr0) * (long long)ldb + sjx * 8) * 2;
    dA[cc] = ldsc + ch * 4096;
    dB[cc] = ldsc + 32768 + ch * 4096;
  }

  f32x4 acc[4][4];
  #pragma unroll
  for (int m = 0; m < 4; ++m)
    #pragma unroll
    for (int n = 0; n < 4; ++n)
      #pragma unroll
      for (int q = 0; q < 4; ++q) acc[m][n][q] = 0.0f;

  auto LOADF = [&](int S, short8* av, short8* bv) {
    #pragma unroll
    for (int m = 0; m < 4; ++m) av[m] = *(const short8*)(ldsc + (preA[m] + S * 1024));
    #pragma unroll
    for (int n = 0; n < 4; ++n) bv[n] = *(const short8*)(ldsc + (preB[n] + S * 1024));
  };
  auto MF = [&](short8* av, short8* bv) {
    __builtin_amdgcn_s_setprio(1);
    #pragma unroll
    for (int m = 0; m < 4; ++m)
      #pragma unroll
      for (int n = 0; n < 4; ++n)
        acc[m][n] = __builtin_amdgcn_mfma_f32_16x16x32_bf16(av[m], bv[n], acc[m][n], 0, 0, 0);
    __builtin_amdgcn_s_setprio(0);
  };

  const int NT = Ktot >> 5;   // multiple of 4
  #pragma unroll
  for (int p = 0; p < 3; ++p)
    #pragma unroll
    for (int cc = 0; cc < 2; ++cc) {
      async_copy16(gA[cc] + p * 64, dA[cc] + p * 1024);
      async_copy16(gB[cc] + p * 64, dB[cc] + p * 1024);
    }
  asm volatile("s_waitcnt vmcnt(4)" ::: "memory");   // tiles 0,1 landed
  __builtin_amdgcn_s_barrier();

  short8 avA[4], bvA[4], avB[4], bvB[4];
  LOADF(0, avA, bvA);

  for (int tg = 0; tg < NT; tg += 4) {
    #pragma unroll
    for (int T4 = 0; T4 < 4; ++T4) {
      const int tt = tg + T4;
      if (tt + 3 < NT) {
        const int S = (T4 + 3) & 3;
        #pragma unroll
        for (int cc = 0; cc < 2; ++cc) {
          async_copy16(gA[cc] + (T4 + 3) * 64, dA[cc] + S * 1024);
          async_copy16(gB[cc] + (T4 + 3) * 64, dB[cc] + S * 1024);
        }
      }
      if ((T4 & 1) == 0) { LOADF((T4 + 1) & 3, avB, bvB); MF(avA, bvA); }
      else               { LOADF((T4 + 1) & 3, avA, bvA); MF(avB, bvB); }
      asm volatile("s_waitcnt vmcnt(4)" ::: "memory");
      __builtin_amdgcn_s_barrier();
    }
    #pragma unroll
    for (int cc = 0; cc < 2; ++cc) { gA[cc] += 256; gB[cc] += 256; }
  }

  #pragma unroll
  for (int m = 0; m < 4; ++m) {
    #pragma unroll
    for (int n = 0; n < 4; ++n) {
      const long long col = bcol + wc + n * 16 + l15;
      #pragma unroll
      for (int q = 0; q < 4; ++q) {
        const long long row = brow + wr + m * 16 + jhi * 4 + q;
        Cout[row * ldc + col] = acc[m][n][q];
      }
    }
  }
}

// ---------------- 256x256 GEMM: slot-interleaved LDS, hoisted addrs, x4 unroll ------
// A chunks 0..15 at c*4096 + S*1024 (64 KiB); B region at +65536.
template<int EPI>
__global__ __launch_bounds__(512, 2) void k_gemm256(
    const unsigned short* __restrict__ A, int lda,
    const unsigned short* __restrict__ B, int ldb,
    int Ktot, int nx, int ny,
    float* __restrict__ Cout, int ldc,
    const float* __restrict__ rowscale, const float* __restrict__ vcol) {
  __shared__ unsigned short lds[65536];   // 128 KiB
  char* ldsc = (char*)lds;
  const int tid = threadIdx.x;
  const int lane = tid & 63;
  const int w = tid >> 6;            // 0..7
  const int wm = w >> 2, wn = w & 3;

  // XCD-aware mapping: co-resident blocks on an XCD share one A-panel.
  // HW round-robins original blockIdx across 8 XCDs: xcd = bid&7.
  const int bid = blockIdx.x;
  const int x = bid & 7;
  const int j = bid >> 3;
  const int bx = x * (nx >> 3) + j / ny;
  const int by = j % ny;
  const long long brow = (long long)bx * 256;
  const long long bcol = (long long)by * 256;

  const int c0 = w * 2;
  const int sr0 = lane >> 2, sj = lane & 3;
  const int l15 = lane & 15, jhi = lane >> 4;
  const int jx = jhi ^ ((l15 >> 1) & 3);
  const int sjx = sj ^ ((sr0 >> 1) & 3);

  int preA[8], preB[4];
  #pragma unroll
  for (int m = 0; m < 8; ++m) preA[m] = (wm * 8 + m) * 4096 + l15 * 64 + jx * 16;
  #pragma unroll
  for (int n = 0; n < 4; ++n) preB[n] = 65536 + (wn * 4 + n) * 4096 + l15 * 64 + jx * 16;

  const char* gA[2]; const char* gB[2]; char* dA[2]; char* dB[2];
  #pragma unroll
  for (int cc = 0; cc < 2; ++cc) {
    const int ch = c0 + cc;
    gA[cc] = (const char*)A + ((brow + ch * 16 + sr0) * (long long)lda + sjx * 8) * 2;
    gB[cc] = (const char*)B + ((bcol + ch * 16 + sr0) * (long long)ldb + sjx * 8) * 2;
    dA[cc] = ldsc + ch * 4096;
    dB[cc] = ldsc + 65536 + ch * 4096;
  }

  f32x4 acc[8][4];
  #pragma unroll
  for (int m = 0; m < 8; ++m)
    #pragma unroll
    for (int n = 0; n < 4; ++n)
      #pragma unroll
      for (int q = 0; q < 4; ++q) acc[m][n][q] = 0.0f;

  auto LOADF = [&](int S, short8* av, short8* bv) {
    #pragma unroll
    for (int m = 0; m < 8; ++m) av[m] = *(const short8*)(ldsc + (preA[m] + S * 1024));
    #pragma unroll
    for (int n = 0; n < 4; ++n) bv[n] = *(const short8*)(ldsc + (preB[n] + S * 1024));
  };
  auto MF = [&](short8* av, short8* bv) {
    __builtin_amdgcn_s_setprio(1);
    #pragma unroll
    for (int m = 0; m < 8; ++m)
      #pragma unroll
      for (int n = 0; n < 4; ++n)
        acc[m][n] = __builtin_amdgcn_mfma_f32_16x16x32_bf16(av[m], bv[n], acc[m][n], 0, 0, 0);
    __builtin_amdgcn_s_setprio(0);
  };

  const int NT = Ktot >> 5;   // multiple of 4
  #pragma unroll
  for (int p = 0; p < 3; ++p)
    #pragma unroll
    for (int cc = 0; cc < 2; ++cc) {
      async_copy16(gA[cc] + p * 64, dA[cc] + p * 1024);
      async_copy16(gB[cc] + p * 64, dB[cc] + p * 1024);
    }
  asm volatile("s_waitcnt vmcnt(4)" ::: "memory");   // tiles 0,1 landed
  __builtin_amdgcn_s_barrier();

  short8 avA[8], bvA[4], avB[8], bvB[4];
  LOADF(0, avA, bvA);

  for (int tg = 0; tg < NT; tg += 4) {
    #pragma unroll
    for (int T4 = 0; T4 < 4; ++T4) {
      const int tt = tg + T4;
      if (tt + 3 < NT) {
        const int S = (T4 + 3) & 3;
        #pragma unroll
        for (int cc = 0; cc < 2; ++cc) {
          async_copy16(gA[cc] + (T4 + 3) * 64, dA[cc] + S * 1024);
          async_copy16(gB[cc] + (T4 + 3) * 64, dB[cc] + S * 1024);
        }
      }
      if ((T4 & 1) == 0) { LOADF((T4 + 1) & 3, avB, bvB); MF(avA, bvA); }
      else               { LOADF((T4 + 1) & 3, avA, bvA); MF(avB, bvB); }
      asm volatile("s_waitcnt vmcnt(4)" ::: "memory");
      __builtin_amdgcn_s_barrier();
    }
    #pragma unroll
    for (int cc = 0; cc < 2; ++cc) { gA[cc] += 256; gB[cc] += 256; }
  }

  // epilogue: C/D layout col = lane&15, row = (lane>>4)*4 + q
  #pragma unroll
  for (int m = 0; m < 8; ++m) {
    #pragma unroll
    for (int n = 0; n < 4; ++n) {
      const long long col = bcol + wn * 64 + n * 16 + l15;
      float cs = 1.0f;
      if (EPI == 1) cs = 1.0f + vcol[col];
      #pragma unroll
      for (int q = 0; q < 4; ++q) {
        const long long row = brow + wm * 128 + m * 16 + jhi * 4 + q;
        float val = acc[m][n][q];
        if (EPI == 1) val *= rowscale[row] * cs;
        Cout[row * ldc + col] = val;
      }
    }
  }
}

extern "C" void kernel_launch(void* const* d_in, const int* in_sizes, int n_in,
                              void* d_out, int out_size, void* d_ws, size_t ws_size,
                              hipStream_t stream) {
  const float* x   = (const float*)d_in[0];
  const float* W   = (const float*)d_in[1];
  const float* U   = (const float*)d_in[2];
  const float* V   = (const float*)d_in[3];
  const float* lam = (const float*)d_in[4];
  const float* v   = (const float*)d_in[5];
  const float* Wg1 = (const float*)d_in[6];
  const float* Wg2 = (const float*)d_in[7];
  float* out = (float*)d_out;

  const int N = in_sizes[0] / D_DIM;        // 16384
  const int k = in_sizes[2] / D_DIM;        // SVD rank (~566)
  const int k_pad = (k + 127) & ~127;       // multiple of 128
  const int Ktot = D_DIM + k_pad;           // 2688 (NT multiple of 4)

  char* ws = (char*)d_ws;
  size_t off = 0;
  auto alloc = [&](size_t bytes) -> void* {
    void* p = ws + off;
    off += (bytes + 255) & ~(size_t)255;
    return p;
  };
  unsigned short* Acat = (unsigned short*)alloc((size_t)N * Ktot * 2);     // [x | xu*coef]
  unsigned short* Bcat = (unsigned short*)alloc((size_t)D_DIM * Ktot * 2); // [W^T | V]
  unsigned short* Ukt  = (unsigned short*)alloc((size_t)k_pad * D_DIM * 2);
  float*          xu   = (float*)alloc((size_t)N * k_pad * 4);
  float*          rs   = (float*)alloc((size_t)N * 4);
  if (off > ws_size) return;

  // 1) conversions into concatenated layouts
  k_cvt_bf16s<<<2048, 256, 0, stream>>>(x, Acat, N, D_DIM, Ktot);
  k_transpose_bf16<<<dim3(D_DIM / 32, D_DIM / 32), dim3(32, 8), 0, stream>>>(
      W, D_DIM, D_DIM, D_DIM, Bcat, D_DIM, Ktot);                 // W^T -> Bcat[:, :2048]
  k_transpose_bf16<<<dim3(k_pad / 32, D_DIM / 32), dim3(32, 8), 0, stream>>>(
      U, D_DIM, k, k, Ukt, k_pad, D_DIM);                         // U^T (padded)
  k_pad_bf16<<<512, 256, 0, stream>>>(V, Bcat + D_DIM, D_DIM, k, k_pad, Ktot);

  // 2) xu = x @ U_k   [N, k_pad] f32  (A = Acat[:, :2048])
  k_gemm128<<<dim3(N / 128, k_pad / 128), 256, 0, stream>>>(
      Acat, Ktot, Ukt, D_DIM, D_DIM, xu, k_pad);

  // 3) routing -> Acat[:, 2048:], rowscale
  k_route<<<N / 4, 256, 0, stream>>>(xu, k, k_pad, Wg1, Wg2, lam, Acat, Ktot, rs, N);

  // 4) fused GEMM: out = (Acat @ Bcat^T) * rowscale * (1+v)
  const int nx = N / 256;                 // 64 (multiple of 8)
  const int ny = D_DIM / 256;             // 8
  k_gemm256<1><<<nx * ny, 512, 0, stream>>>(
      Acat, Ktot, Bcat, Ktot, Ktot, nx, ny,
      out, D_DIM, rs, v);
}

// Round 7
// 352.894 us; speedup vs baseline: 1.3942x; 1.3942x over previous
//
#include <hip/hip_runtime.h>
#include <hip/hip_bf16.h>

#define D_DIM 2048
#define E_DIM 8

typedef __attribute__((ext_vector_type(8))) short short8;
typedef __attribute__((ext_vector_type(4))) float f32x4;

__device__ __forceinline__ unsigned short f2bf(float f) {
  union { float f; unsigned int u; } v; v.f = f;
  unsigned int u = v.u;
  u += 0x7FFFu + ((u >> 16) & 1u);   // round-to-nearest-even
  return (unsigned short)(u >> 16);
}

__device__ __forceinline__ void async_copy16(const void* g, void* l) {
  __builtin_amdgcn_global_load_lds((const __attribute__((address_space(1))) void*)g,
                                   (__attribute__((address_space(3))) void*)l,
                                   16, 0, 0);
}

// ---------------- f32 -> bf16 bulk convert ----------------
__global__ void k_cvt_bf16(const float* __restrict__ in,
                           unsigned short* __restrict__ out, long long n) {
  long long i = ((long long)blockIdx.x * blockDim.x + threadIdx.x) * 8;
  const long long stride = (long long)gridDim.x * blockDim.x * 8;
  for (; i < n; i += stride) {
    float4 a = *(const float4*)(in + i);
    float4 b = *(const float4*)(in + i + 4);
    short8 r;
    r[0] = (short)f2bf(a.x); r[1] = (short)f2bf(a.y);
    r[2] = (short)f2bf(a.z); r[3] = (short)f2bf(a.w);
    r[4] = (short)f2bf(b.x); r[5] = (short)f2bf(b.y);
    r[6] = (short)f2bf(b.z); r[7] = (short)f2bf(b.w);
    *(short8*)(out + i) = r;
  }
}

// ---------------- transpose f32 -> bf16 (with zero pad) ----------------
__global__ void k_transpose_bf16(const float* __restrict__ in, int in_rows, int in_cols,
                                 int in_ld, unsigned short* __restrict__ out, int out_rows) {
  __shared__ float tile[32][33];
  const int tx = threadIdx.x;  // 0..31
  const int ty = threadIdx.y;  // 0..7
  const int c = blockIdx.x * 32 + tx;
  #pragma unroll
  for (int i = 0; i < 4; ++i) {
    const int r = blockIdx.y * 32 + ty + i * 8;
    float vv = 0.0f;
    if (r < in_rows && c < in_cols) vv = in[(size_t)r * in_ld + c];
    tile[ty + i * 8][tx] = vv;
  }
  __syncthreads();
  const int oc = blockIdx.y * 32 + tx;   // = original row
  #pragma unroll
  for (int i = 0; i < 4; ++i) {
    const int orow = blockIdx.x * 32 + ty + i * 8;  // = original col (padded)
    if (orow < out_rows && oc < in_rows)
      out[(size_t)orow * in_rows + oc] = f2bf(tile[tx][ty + i * 8]);
  }
}

// ---------------- pad-copy f32 -> bf16 (row-major, pad cols with 0) ----------------
__global__ void k_pad_bf16(const float* __restrict__ in, unsigned short* __restrict__ out,
                           int rows, int cols, int cols_pad) {
  long long idx = (long long)blockIdx.x * blockDim.x + threadIdx.x;
  const long long total = (long long)rows * cols_pad;
  const long long stride = (long long)gridDim.x * blockDim.x;
  for (; idx < total; idx += stride) {
    const int r = (int)(idx / cols_pad);
    const int c = (int)(idx % cols_pad);
    out[idx] = (c < cols) ? f2bf(in[(size_t)r * cols + c]) : (unsigned short)0;
  }
}

// ---------------- routing ----------------
__global__ void k_route(const float* __restrict__ xu, int k, int k_pad,
                        const float* __restrict__ Wg1, const float* __restrict__ Wg2,
                        const float* __restrict__ lam,  // [E][k]
                        unsigned short* __restrict__ A2, float* __restrict__ rowscale,
                        int Nrows) {
  const int w = threadIdx.x >> 6;
  const int lane = threadIdx.x & 63;
  const int row = blockIdx.x * 4 + w;
  if (row >= Nrows) return;
  const float* xr = xu + (size_t)row * k_pad;
  float s = 0.0f;
  for (int kk = lane; kk < k; kk += 64) s += xr[kk] * Wg1[kk];
  #pragma unroll
  for (int off = 32; off; off >>= 1) s += __shfl_xor(s, off);
  float lg[E_DIM];
  float mx = -INFINITY;
  #pragma unroll
  for (int e = 0; e < E_DIM; ++e) { lg[e] = s * Wg2[e]; mx = fmaxf(mx, lg[e]); }
  float Z = 0.0f;
  #pragma unroll
  for (int e = 0; e < E_DIM; ++e) { lg[e] = expf(lg[e] - mx); Z += lg[e]; }
  float g[E_DIM]; float gsum = 0.0f;
  #pragma unroll
  for (int e = 0; e < E_DIM; ++e) { g[e] = lg[e] / Z; gsum += g[e]; }
  const float inv = 1.0f / gsum;
  if (lane == 0) rowscale[row] = gsum;
  unsigned short* arow = A2 + (size_t)row * k_pad;
  for (int kk = lane; kk < k_pad; kk += 64) {
    if (kk < k) {
      float c = 0.0f;
      #pragma unroll
      for (int e = 0; e < E_DIM; ++e) c += g[e] * lam[(size_t)e * k + kk];
      arow[kk] = f2bf(xr[kk] * (c * inv));
    } else {
      arow[kk] = 0;
    }
  }
}

// ---------------- 128x128 4-wave, 4-slot rotation, reg-double-buffered frags ----------
__global__ __launch_bounds__(256, 2) void k_gemm128(
    const unsigned short* __restrict__ A, long long lda,
    const unsigned short* __restrict__ B, long long ldb,
    int Ktot, float* __restrict__ Cout, int ldc) {
  __shared__ unsigned short lds[4 * 8192];   // 64 KiB: slot = A[128][32] + B[128][32]
  const int tid = threadIdx.x;
  const int lane = tid & 63;
  const int w = tid >> 6;            // 0..3
  const long long brow = (long long)blockIdx.x * 128;
  const long long bcol = (long long)blockIdx.y * 128;
  const int c0 = w * 2;
  const int sr0 = lane >> 2;
  const int sj  = lane & 3;
  const int l15 = lane & 15;
  const int jhi = lane >> 4;
  const int wr = (w >> 1) * 64;
  const int wc = (w & 1) * 64;

  auto stage = [&](int tt) {
    unsigned short* dstA = lds + (tt & 3) * 8192;
    #pragma unroll
    for (int c = 0; c < 2; ++c) {
      const int chunk = c0 + c;
      const int lrow = chunk * 16 + sr0;
      const int jj = sj ^ ((lrow >> 1) & 3);
      async_copy16(A + (brow + lrow) * lda + (long long)tt * 32 + jj * 8,
                   (void*)(dstA + chunk * 512));
      async_copy16(B + (bcol + lrow) * ldb + (long long)tt * 32 + jj * 8,
                   (void*)(dstA + 4096 + chunk * 512));
    }
  };

  auto load_frags = [&](int tt, short8* av, short8* bv) {
    const unsigned short* Areg = lds + (tt & 3) * 8192;
    const unsigned short* Breg = Areg + 4096;
    #pragma unroll
    for (int m = 0; m < 4; ++m) {
      const int row = wr + m * 16 + l15;
      const int jj = jhi ^ ((row >> 1) & 3);
      av[m] = *(const short8*)(Areg + row * 32 + jj * 8);
    }
    #pragma unroll
    for (int n = 0; n < 4; ++n) {
      const int row = wc + n * 16 + l15;
      const int jj = jhi ^ ((row >> 1) & 3);
      bv[n] = *(const short8*)(Breg + row * 32 + jj * 8);
    }
  };

  f32x4 acc[4][4];
  #pragma unroll
  for (int m = 0; m < 4; ++m)
    #pragma unroll
    for (int n = 0; n < 4; ++n)
      #pragma unroll
      for (int j = 0; j < 4; ++j) acc[m][n][j] = 0.0f;

  auto do_mfma = [&](short8* av, short8* bv) {
    __builtin_amdgcn_s_setprio(1);
    #pragma unroll
    for (int m = 0; m < 4; ++m)
      #pragma unroll
      for (int n = 0; n < 4; ++n)
        acc[m][n] = __builtin_amdgcn_mfma_f32_16x16x32_bf16(av[m], bv[n], acc[m][n], 0, 0, 0);
    __builtin_amdgcn_s_setprio(0);
  };

  const int NT = Ktot >> 5;   // even (K multiple of 64)
  stage(0); stage(1); stage(2);
  asm volatile("s_waitcnt vmcnt(4)" ::: "memory");   // tiles 0,1 landed
  __builtin_amdgcn_s_barrier();

  short8 avA[4], bvA[4], avB[4], bvB[4];
  load_frags(0, avA, bvA);

  for (int t = 0; t < NT; t += 2) {
    if (t + 3 < NT) stage(t + 3);
    load_frags(t + 1, avB, bvB);
    do_mfma(avA, bvA);
    asm volatile("s_waitcnt vmcnt(4)" ::: "memory");
    __builtin_amdgcn_s_barrier();
    if (t + 4 < NT) stage(t + 4);
    if (t + 2 < NT) load_frags(t + 2, avA, bvA);
    do_mfma(avB, bvB);
    asm volatile("s_waitcnt vmcnt(4)" ::: "memory");
    __builtin_amdgcn_s_barrier();
  }

  #pragma unroll
  for (int m = 0; m < 4; ++m) {
    #pragma unroll
    for (int n = 0; n < 4; ++n) {
      const long long col = bcol + wc + n * 16 + l15;
      #pragma unroll
      for (int j = 0; j < 4; ++j) {
        const long long row = brow + wr + m * 16 + jhi * 4 + j;
        Cout[row * ldc + col] = acc[m][n][j];
      }
    }
  }
}

// ---------------- 256x256 8-wave, pair-slot double-buffer (BK=64 periods) ----------
// 2 pair-slots x 64 KiB. Pair p = K-tiles {2p, 2p+1} in slot p&1
// (tile e of pair at slotbase + e*16384 shorts: A 8192 shorts, then B 8192).
// Period p: stage pair p+1 (issued FIRST -> ~full period of latency cover)
//           -> 24 ds_read (both tiles' frags) -> 64 MFMA -> vmcnt(0) -> barrier.
// Safety: write slot = (p+1)&1 != read slot; barrier separates last reads of a
// slot from its next overwrite; vmcnt(0)+barrier => pair p+1 landed for all waves.
template<int EPI>
__global__ __launch_bounds__(512, 2) void k_gemm256(
    const unsigned short* __restrict__ A0, int lda0,
    const unsigned short* __restrict__ A1, int lda1,
    const unsigned short* __restrict__ B0, int ldb0,
    const unsigned short* __restrict__ B1, int ldb1,
    int ka0, int Ktot, int gridM,
    float* __restrict__ Cout, int ldc,
    const float* __restrict__ rowscale, const float* __restrict__ vcol) {
  __shared__ unsigned short lds[65536];   // 128 KiB
  const int tid = threadIdx.x;
  const int lane = tid & 63;
  const int w = tid >> 6;            // 0..7
  const int wm = w >> 2;             // 0..1  (M half)
  const int wn = w & 3;              // 0..3  (N quarter)

  // bijective XCD swizzle (grid size divisible by 8) — R4-proven
  int bid = blockIdx.x;
  const int cpx = gridDim.x >> 3;
  bid = (bid & 7) * cpx + (bid >> 3);
  const int bx = bid % gridM;
  const int by = bid / gridM;
  const long long brow = (long long)bx * 256;
  const long long bcol = (long long)by * 256;

  const int c0 = w * 2;
  const int sr0 = lane >> 2;
  const int sj  = lane & 3;
  const int l15 = lane & 15;
  const int jhi = lane >> 4;

  // stage one K-tile tt into region base (A at base, B at base+8192 shorts)
  auto stage_tile = [&](int tt, unsigned short* base) {
    const int k0 = tt * 32;
    const unsigned short* PA; long long ldA; long long kA;
    const unsigned short* PB; long long ldB; long long kB;
    if (k0 < ka0) { PA = A0; ldA = lda0; kA = k0;       PB = B0; ldB = ldb0; kB = k0; }
    else          { PA = A1; ldA = lda1; kA = k0 - ka0; PB = B1; ldB = ldb1; kB = k0 - ka0; }
    #pragma unroll
    for (int c = 0; c < 2; ++c) {
      const int chunk = c0 + c;
      const int lrow = chunk * 16 + sr0;
      const int jj = sj ^ ((lrow >> 1) & 3);
      async_copy16(PA + (brow + lrow) * ldA + kA + jj * 8, (void*)(base + chunk * 512));
      async_copy16(PB + (bcol + lrow) * ldB + kB + jj * 8, (void*)(base + 8192 + chunk * 512));
    }
  };

  auto load_frags = [&](const unsigned short* base, short8* av, short8* bv) {
    const unsigned short* Breg = base + 8192;
    #pragma unroll
    for (int m = 0; m < 8; ++m) {
      const int row = wm * 128 + m * 16 + l15;
      const int jj = jhi ^ ((row >> 1) & 3);
      av[m] = *(const short8*)(base + row * 32 + jj * 8);
    }
    #pragma unroll
    for (int n = 0; n < 4; ++n) {
      const int row = wn * 64 + n * 16 + l15;
      const int jj = jhi ^ ((row >> 1) & 3);
      bv[n] = *(const short8*)(Breg + row * 32 + jj * 8);
    }
  };

  f32x4 acc[8][4];
  #pragma unroll
  for (int m = 0; m < 8; ++m)
    #pragma unroll
    for (int n = 0; n < 4; ++n)
      #pragma unroll
      for (int j = 0; j < 4; ++j) acc[m][n][j] = 0.0f;

  auto do_mfma = [&](short8* av, short8* bv) {
    #pragma unroll
    for (int m = 0; m < 8; ++m)
      #pragma unroll
      for (int n = 0; n < 4; ++n)
        acc[m][n] = __builtin_amdgcn_mfma_f32_16x16x32_bf16(av[m], bv[n], acc[m][n], 0, 0, 0);
  };

  const int NT = Ktot >> 5;      // multiple of 2 (Ktot multiple of 64)
  const int NP = NT >> 1;        // pair count

  // prologue: stage pair 0
  stage_tile(0, lds);
  stage_tile(1, lds + 16384);
  asm volatile("s_waitcnt vmcnt(0)" ::: "memory");
  __builtin_amdgcn_s_barrier();

  short8 av0[8], bv0[4], av1[8], bv1[4];

  for (int p = 0; p < NP; ++p) {
    unsigned short* cur = lds + (p & 1) * 32768;
    unsigned short* nxt = lds + ((p + 1) & 1) * 32768;
    // issue next pair's staging FIRST: ~full period (>2000 cyc) to land
    if (p + 1 < NP) {
      stage_tile(2 * (p + 1),     nxt);
      stage_tile(2 * (p + 1) + 1, nxt + 16384);
    }
    // read both tiles' fragments (compiler inserts partial lgkmcnt before MFMAs)
    load_frags(cur,         av0, bv0);
    load_frags(cur + 16384, av1, bv1);
    __builtin_amdgcn_s_setprio(1);
    do_mfma(av0, bv0);
    do_mfma(av1, bv1);
    __builtin_amdgcn_s_setprio(0);
    // drain (nearly free: loads were issued at period start) + barrier
    asm volatile("s_waitcnt vmcnt(0)" ::: "memory");
    __builtin_amdgcn_s_barrier();
  }

  // epilogue: C/D layout col = lane&15, row = (lane>>4)*4 + j
  #pragma unroll
  for (int m = 0; m < 8; ++m) {
    #pragma unroll
    for (int n = 0; n < 4; ++n) {
      const long long col = bcol + wn * 64 + n * 16 + l15;
      float cs = 1.0f;
      if (EPI == 1) cs = 1.0f + vcol[col];
      #pragma unroll
      for (int j = 0; j < 4; ++j) {
        const long long row = brow + wm * 128 + m * 16 + jhi * 4 + j;
        float val = acc[m][n][j];
        if (EPI == 1) val *= rowscale[row] * cs;
        Cout[row * ldc + col] = val;
      }
    }
  }
}

extern "C" void kernel_launch(void* const* d_in, const int* in_sizes, int n_in,
                              void* d_out, int out_size, void* d_ws, size_t ws_size,
                              hipStream_t stream) {
  const float* x   = (const float*)d_in[0];
  const float* W   = (const float*)d_in[1];
  const float* U   = (const float*)d_in[2];
  const float* V   = (const float*)d_in[3];
  const float* lam = (const float*)d_in[4];
  const float* v   = (const float*)d_in[5];
  const float* Wg1 = (const float*)d_in[6];
  const float* Wg2 = (const float*)d_in[7];
  float* out = (float*)d_out;

  const int N = in_sizes[0] / D_DIM;        // 16384
  const int k = in_sizes[2] / D_DIM;        // SVD rank (~566)
  const int k_pad = (k + 127) & ~127;       // multiple of 128

  char* ws = (char*)d_ws;
  size_t off = 0;
  auto alloc = [&](size_t bytes) -> void* {
    void* p = ws + off;
    off += (bytes + 255) & ~(size_t)255;
    return p;
  };
  unsigned short* xb  = (unsigned short*)alloc((size_t)N * D_DIM * 2);
  unsigned short* Wt  = (unsigned short*)alloc((size_t)D_DIM * D_DIM * 2);
  unsigned short* Ukt = (unsigned short*)alloc((size_t)k_pad * D_DIM * 2);
  unsigned short* Vb  = (unsigned short*)alloc((size_t)D_DIM * k_pad * 2);
  float*          xu  = (float*)alloc((size_t)N * k_pad * 4);
  unsigned short* A2  = (unsigned short*)alloc((size_t)N * k_pad * 2);
  float*          rs  = (float*)alloc((size_t)N * 4);
  if (off > ws_size) return;

  // 1) conversions
  k_cvt_bf16<<<2048, 256, 0, stream>>>(x, xb, (long long)N * D_DIM);
  k_transpose_bf16<<<dim3(D_DIM / 32, D_DIM / 32), dim3(32, 8), 0, stream>>>(
      W, D_DIM, D_DIM, D_DIM, Wt, D_DIM);
  k_transpose_bf16<<<dim3(k_pad / 32, D_DIM / 32), dim3(32, 8), 0, stream>>>(
      U, D_DIM, k, k, Ukt, k_pad);
  k_pad_bf16<<<512, 256, 0, stream>>>(V, Vb, D_DIM, k, k_pad);

  // 2) xu = x @ U_k   [N, k_pad] f32
  k_gemm128<<<dim3(N / 128, k_pad / 128), 256, 0, stream>>>(
      xb, D_DIM, Ukt, D_DIM, D_DIM, xu, k_pad);

  // 3) routing -> A2, rowscale
  k_route<<<N / 4, 256, 0, stream>>>(xu, k, k_pad, Wg1, Wg2, lam, A2, rs, N);

  // 4) fused GEMM: out = (x@W + A2@V^T) * rowscale * (1+v)  [256^2, pair-slot dbuf]
  const int gridM = N / 256;                 // 64
  const int gridN = D_DIM / 256;             // 8
  k_gemm256<1><<<gridM * gridN, 512, 0, stream>>>(
      xb, D_DIM, A2, k_pad,
      Wt, D_DIM, Vb, k_pad,
      D_DIM, D_DIM + k_pad, gridM,
      out, D_DIM, rs, v);
}

// Round 8
// 327.815 us; speedup vs baseline: 1.5009x; 1.0765x over previous
//
#include <hip/hip_runtime.h>
#include <hip/hip_bf16.h>

#define D_DIM 2048
#define E_DIM 8

typedef __attribute__((ext_vector_type(8))) short short8;
typedef __attribute__((ext_vector_type(4))) float f32x4;

__device__ __forceinline__ unsigned short f2bf(float f) {
  union { float f; unsigned int u; } v; v.f = f;
  unsigned int u = v.u;
  u += 0x7FFFu + ((u >> 16) & 1u);   // round-to-nearest-even
  return (unsigned short)(u >> 16);
}

__device__ __forceinline__ float bf2f(unsigned short h) {
  union { unsigned int u; float f; } v; v.u = ((unsigned int)h) << 16;
  return v.f;
}

__device__ __forceinline__ void async_copy16(const void* g, void* l) {
  __builtin_amdgcn_global_load_lds((const __attribute__((address_space(1))) void*)g,
                                   (__attribute__((address_space(3))) void*)l,
                                   16, 0, 0);
}

// ---------------- f32 -> bf16 bulk convert ----------------
__global__ void k_cvt_bf16(const float* __restrict__ in,
                           unsigned short* __restrict__ out, long long n) {
  long long i = ((long long)blockIdx.x * blockDim.x + threadIdx.x) * 8;
  const long long stride = (long long)gridDim.x * blockDim.x * 8;
  for (; i < n; i += stride) {
    float4 a = *(const float4*)(in + i);
    float4 b = *(const float4*)(in + i + 4);
    short8 r;
    r[0] = (short)f2bf(a.x); r[1] = (short)f2bf(a.y);
    r[2] = (short)f2bf(a.z); r[3] = (short)f2bf(a.w);
    r[4] = (short)f2bf(b.x); r[5] = (short)f2bf(b.y);
    r[6] = (short)f2bf(b.z); r[7] = (short)f2bf(b.w);
    *(short8*)(out + i) = r;
  }
}

// ---------------- transpose f32 -> bf16 (with zero pad) ----------------
__global__ void k_transpose_bf16(const float* __restrict__ in, int in_rows, int in_cols,
                                 int in_ld, unsigned short* __restrict__ out, int out_rows) {
  __shared__ float tile[32][33];
  const int tx = threadIdx.x;  // 0..31
  const int ty = threadIdx.y;  // 0..7
  const int c = blockIdx.x * 32 + tx;
  #pragma unroll
  for (int i = 0; i < 4; ++i) {
    const int r = blockIdx.y * 32 + ty + i * 8;
    float vv = 0.0f;
    if (r < in_rows && c < in_cols) vv = in[(size_t)r * in_ld + c];
    tile[ty + i * 8][tx] = vv;
  }
  __syncthreads();
  const int oc = blockIdx.y * 32 + tx;   // = original row
  #pragma unroll
  for (int i = 0; i < 4; ++i) {
    const int orow = blockIdx.x * 32 + ty + i * 8;  // = original col (padded)
    if (orow < out_rows && oc < in_rows)
      out[(size_t)orow * in_rows + oc] = f2bf(tile[tx][ty + i * 8]);
  }
}

// ---------------- pad-copy f32 -> bf16 (row-major, pad cols with 0) ----------------
__global__ void k_pad_bf16(const float* __restrict__ in, unsigned short* __restrict__ out,
                           int rows, int cols, int cols_pad) {
  long long idx = (long long)blockIdx.x * blockDim.x + threadIdx.x;
  const long long total = (long long)rows * cols_pad;
  const long long stride = (long long)gridDim.x * blockDim.x;
  for (; idx < total; idx += stride) {
    const int r = (int)(idx / cols_pad);
    const int c = (int)(idx % cols_pad);
    out[idx] = (c < cols) ? f2bf(in[(size_t)r * cols + c]) : (unsigned short)0;
  }
}

// ---------------- u1 = U @ Wg1  (f32, one wave per output row d) ----------------
__global__ void k_u1(const float* __restrict__ U, const float* __restrict__ Wg1,
                     float* __restrict__ u1, int D, int k) {
  const int w = threadIdx.x >> 6;
  const int lane = threadIdx.x & 63;
  const int d = blockIdx.x * 4 + w;
  if (d >= D) return;
  const float* row = U + (size_t)d * k;
  float s = 0.0f;
  for (int j = lane; j < k; j += 64) s += row[j] * Wg1[j];
  #pragma unroll
  for (int off = 32; off; off >>= 1) s += __shfl_xor(s, off);
  if (lane == 0) u1[d] = s;
}

// ---------------- gate: s = xb.u1 ; g = softmax(s * Wg2) -> g8[N][8] ----------------
__global__ void k_gate(const unsigned short* __restrict__ xb,
                       const float* __restrict__ u1, const float* __restrict__ Wg2,
                       float* __restrict__ g8, int Nrows) {
  const int w = threadIdx.x >> 6;
  const int lane = threadIdx.x & 63;
  const int row = blockIdx.x * 4 + w;
  if (row >= Nrows) return;
  const unsigned short* xr = xb + (size_t)row * D_DIM;
  float s = 0.0f;
  #pragma unroll
  for (int t = 0; t < D_DIM / 512; ++t) {
    const int base = (t * 64 + lane) * 8;
    short8 v = *(const short8*)(xr + base);
    float4 ua = *(const float4*)(u1 + base);
    float4 ub = *(const float4*)(u1 + base + 4);
    s += bf2f((unsigned short)v[0]) * ua.x + bf2f((unsigned short)v[1]) * ua.y +
         bf2f((unsigned short)v[2]) * ua.z + bf2f((unsigned short)v[3]) * ua.w +
         bf2f((unsigned short)v[4]) * ub.x + bf2f((unsigned short)v[5]) * ub.y +
         bf2f((unsigned short)v[6]) * ub.z + bf2f((unsigned short)v[7]) * ub.w;
  }
  #pragma unroll
  for (int off = 32; off; off >>= 1) s += __shfl_xor(s, off);
  if (lane == 0) {
    float lg[E_DIM], mx = -INFINITY;
    #pragma unroll
    for (int e = 0; e < E_DIM; ++e) { lg[e] = s * Wg2[e]; mx = fmaxf(mx, lg[e]); }
    float Z = 0.0f;
    #pragma unroll
    for (int e = 0; e < E_DIM; ++e) { lg[e] = expf(lg[e] - mx); Z += lg[e]; }
    const float inv = 1.0f / Z;
    #pragma unroll
    for (int e = 0; e < E_DIM; ++e) g8[(size_t)row * E_DIM + e] = lg[e] * inv;
  }
}

// ---------------- 128x128 4-wave, 2-slot dbuf, 3 blocks/CU, A2-fused epilogue ------
// Computes xu = xb @ Ukt^T tile, then A2[row][col] = bf16(xu * (g8[row] . lam[:,col])).
__global__ __launch_bounds__(256, 3) void k_gemm128(
    const unsigned short* __restrict__ A, long long lda,
    const unsigned short* __restrict__ B, long long ldb,
    int Ktot,
    const float* __restrict__ g8, const float* __restrict__ lam, int k_real,
    unsigned short* __restrict__ A2, int lda2) {
  __shared__ unsigned short lds[2 * 8192];   // 32 KiB: slot = A[128][32] + B[128][32]
  const int tid = threadIdx.x;
  const int lane = tid & 63;
  const int w = tid >> 6;            // 0..3
  const long long brow = (long long)blockIdx.x * 128;
  const long long bcol = (long long)blockIdx.y * 128;
  const int c0 = w * 2;
  const int sr0 = lane >> 2;
  const int sj  = lane & 3;
  const int l15 = lane & 15;
  const int jhi = lane >> 4;
  const int wr = (w >> 1) * 64;
  const int wc = (w & 1) * 64;

  auto stage = [&](int tt) {
    unsigned short* dstA = lds + (tt & 1) * 8192;
    #pragma unroll
    for (int c = 0; c < 2; ++c) {
      const int chunk = c0 + c;
      const int lrow = chunk * 16 + sr0;
      const int jj = sj ^ ((lrow >> 1) & 3);
      async_copy16(A + (brow + lrow) * lda + (long long)tt * 32 + jj * 8,
                   (void*)(dstA + chunk * 512));
      async_copy16(B + (bcol + lrow) * ldb + (long long)tt * 32 + jj * 8,
                   (void*)(dstA + 4096 + chunk * 512));
    }
  };

  f32x4 acc[4][4];
  #pragma unroll
  for (int m = 0; m < 4; ++m)
    #pragma unroll
    for (int n = 0; n < 4; ++n)
      #pragma unroll
      for (int j = 0; j < 4; ++j) acc[m][n][j] = 0.0f;

  const int NT = Ktot >> 5;
  stage(0);
  asm volatile("s_waitcnt vmcnt(0)" ::: "memory");
  __builtin_amdgcn_s_barrier();

  for (int t = 0; t < NT; ++t) {
    const unsigned short* Areg = lds + (t & 1) * 8192;
    const unsigned short* Breg = Areg + 4096;
    if (t + 1 < NT) stage(t + 1);
    short8 av[4], bv[4];
    #pragma unroll
    for (int m = 0; m < 4; ++m) {
      const int row = wr + m * 16 + l15;
      const int jj = jhi ^ ((row >> 1) & 3);
      av[m] = *(const short8*)(Areg + row * 32 + jj * 8);
    }
    #pragma unroll
    for (int n = 0; n < 4; ++n) {
      const int row = wc + n * 16 + l15;
      const int jj = jhi ^ ((row >> 1) & 3);
      bv[n] = *(const short8*)(Breg + row * 32 + jj * 8);
    }
    __builtin_amdgcn_s_setprio(1);
    #pragma unroll
    for (int m = 0; m < 4; ++m)
      #pragma unroll
      for (int n = 0; n < 4; ++n)
        acc[m][n] = __builtin_amdgcn_mfma_f32_16x16x32_bf16(av[m], bv[n], acc[m][n], 0, 0, 0);
    __builtin_amdgcn_s_setprio(0);
    asm volatile("s_waitcnt vmcnt(0)" ::: "memory");
    __builtin_amdgcn_s_barrier();
  }

  // epilogue: A2 = bf16(acc * coef), coef = sum_e g8[row,e]*lam[e,col]
  // lamE[e][n] hoisted per thread's 4 cols (0 for pad cols)
  float lamE[E_DIM][4];
  #pragma unroll
  for (int n = 0; n < 4; ++n) {
    const long long col = bcol + wc + n * 16 + l15;
    #pragma unroll
    for (int e = 0; e < E_DIM; ++e)
      lamE[e][n] = (col < k_real) ? lam[(size_t)e * k_real + col] : 0.0f;
  }
  #pragma unroll
  for (int m = 0; m < 4; ++m) {
    float coef[4][4];   // [j][n]
    #pragma unroll
    for (int j = 0; j < 4; ++j)
      #pragma unroll
      for (int n = 0; n < 4; ++n) coef[j][n] = 0.0f;
    #pragma unroll
    for (int j = 0; j < 4; ++j) {
      const long long row = brow + wr + m * 16 + jhi * 4 + j;
      const float* gr = g8 + row * E_DIM;
      #pragma unroll
      for (int e = 0; e < E_DIM; ++e) {
        const float ge = gr[e];
        #pragma unroll
        for (int n = 0; n < 4; ++n) coef[j][n] += ge * lamE[e][n];
      }
    }
    #pragma unroll
    for (int n = 0; n < 4; ++n) {
      const long long col = bcol + wc + n * 16 + l15;
      #pragma unroll
      for (int j = 0; j < 4; ++j) {
        const long long row = brow + wr + m * 16 + jhi * 4 + j;
        A2[row * lda2 + col] = f2bf(acc[m][n][j] * coef[j][n]);
      }
    }
  }
}

// ---------------- 256x256 8-wave, 4-slot rotation, reg-double-buffered (R4 best) ----
template<int EPI>
__global__ __launch_bounds__(512, 2) void k_gemm256(
    const unsigned short* __restrict__ A0, int lda0,
    const unsigned short* __restrict__ A1, int lda1,
    const unsigned short* __restrict__ B0, int ldb0,
    const unsigned short* __restrict__ B1, int ldb1,
    int ka0, int Ktot, int gridM,
    float* __restrict__ Cout, int ldc,
    const float* __restrict__ vcol) {
  __shared__ unsigned short lds[4 * 16384];   // 128 KiB
  const int tid = threadIdx.x;
  const int lane = tid & 63;
  const int w = tid >> 6;            // 0..7
  const int wm = w >> 2;             // 0..1  (M half)
  const int wn = w & 3;              // 0..3  (N quarter)

  // bijective XCD swizzle (grid size divisible by 8)
  int bid = blockIdx.x;
  const int cpx = gridDim.x >> 3;
  bid = (bid & 7) * cpx + (bid >> 3);
  const int bx = bid % gridM;
  const int by = bid / gridM;
  const long long brow = (long long)bx * 256;
  const long long bcol = (long long)by * 256;

  const int c0 = w * 2;
  const int sr0 = lane >> 2;
  const int sj  = lane & 3;
  const int l15 = lane & 15;
  const int jhi = lane >> 4;

  auto stage = [&](int tt) {
    const int k0 = tt * 32;
    const unsigned short* PA; long long ldA; long long kA;
    const unsigned short* PB; long long ldB; long long kB;
    if (k0 < ka0) { PA = A0; ldA = lda0; kA = k0;       PB = B0; ldB = ldb0; kB = k0; }
    else          { PA = A1; ldA = lda1; kA = k0 - ka0; PB = B1; ldB = ldb1; kB = k0 - ka0; }
    unsigned short* dst = lds + (tt & 3) * 16384;
    #pragma unroll
    for (int c = 0; c < 2; ++c) {
      const int chunk = c0 + c;
      const int lrow = chunk * 16 + sr0;
      const int jj = sj ^ ((lrow >> 1) & 3);
      async_copy16(PA + (brow + lrow) * ldA + kA + jj * 8, (void*)(dst + chunk * 512));
      async_copy16(PB + (bcol + lrow) * ldB + kB + jj * 8, (void*)(dst + 8192 + chunk * 512));
    }
  };

  auto load_frags = [&](int tt, short8* av, short8* bv) {
    const unsigned short* Areg = lds + (tt & 3) * 16384;
    const unsigned short* Breg = Areg + 8192;
    #pragma unroll
    for (int m = 0; m < 8; ++m) {
      const int row = wm * 128 + m * 16 + l15;
      const int jj = jhi ^ ((row >> 1) & 3);
      av[m] = *(const short8*)(Areg + row * 32 + jj * 8);
    }
    #pragma unroll
    for (int n = 0; n < 4; ++n) {
      const int row = wn * 64 + n * 16 + l15;
      const int jj = jhi ^ ((row >> 1) & 3);
      bv[n] = *(const short8*)(Breg + row * 32 + jj * 8);
    }
  };

  f32x4 acc[8][4];
  #pragma unroll
  for (int m = 0; m < 8; ++m)
    #pragma unroll
    for (int n = 0; n < 4; ++n)
      #pragma unroll
      for (int j = 0; j < 4; ++j) acc[m][n][j] = 0.0f;

  auto do_mfma = [&](short8* av, short8* bv) {
    __builtin_amdgcn_s_setprio(1);
    #pragma unroll
    for (int m = 0; m < 8; ++m)
      #pragma unroll
      for (int n = 0; n < 4; ++n)
        acc[m][n] = __builtin_amdgcn_mfma_f32_16x16x32_bf16(av[m], bv[n], acc[m][n], 0, 0, 0);
    __builtin_amdgcn_s_setprio(0);
  };

  const int NT = Ktot >> 5;   // even (Ktot multiple of 64)
  stage(0); stage(1); stage(2);
  asm volatile("s_waitcnt vmcnt(4)" ::: "memory");   // tiles 0,1 landed
  __builtin_amdgcn_s_barrier();

  short8 avA[8], bvA[4], avB[8], bvB[4];
  load_frags(0, avA, bvA);

  for (int t = 0; t < NT; t += 2) {
    // body t: compute set A, read tile t+1 into set B
    if (t + 3 < NT) stage(t + 3);
    load_frags(t + 1, avB, bvB);
    do_mfma(avA, bvA);
    asm volatile("s_waitcnt vmcnt(4)" ::: "memory");
    __builtin_amdgcn_s_barrier();
    // body t+1: compute set B, read tile t+2 into set A
    if (t + 4 < NT) stage(t + 4);
    if (t + 2 < NT) load_frags(t + 2, avA, bvA);
    do_mfma(avB, bvB);
    asm volatile("s_waitcnt vmcnt(4)" ::: "memory");
    __builtin_amdgcn_s_barrier();
  }

  // epilogue: C/D layout col = lane&15, row = (lane>>4)*4 + j ; out *= (1+v[col])
  #pragma unroll
  for (int m = 0; m < 8; ++m) {
    #pragma unroll
    for (int n = 0; n < 4; ++n) {
      const long long col = bcol + wn * 64 + n * 16 + l15;
      float cs = 1.0f;
      if (EPI == 1) cs = 1.0f + vcol[col];
      #pragma unroll
      for (int j = 0; j < 4; ++j) {
        const long long row = brow + wm * 128 + m * 16 + jhi * 4 + j;
        Cout[row * ldc + col] = acc[m][n][j] * cs;
      }
    }
  }
}

extern "C" void kernel_launch(void* const* d_in, const int* in_sizes, int n_in,
                              void* d_out, int out_size, void* d_ws, size_t ws_size,
                              hipStream_t stream) {
  const float* x   = (const float*)d_in[0];
  const float* W   = (const float*)d_in[1];
  const float* U   = (const float*)d_in[2];
  const float* V   = (const float*)d_in[3];
  const float* lam = (const float*)d_in[4];
  const float* v   = (const float*)d_in[5];
  const float* Wg1 = (const float*)d_in[6];
  const float* Wg2 = (const float*)d_in[7];
  float* out = (float*)d_out;

  const int N = in_sizes[0] / D_DIM;        // 16384
  const int k = in_sizes[2] / D_DIM;        // SVD rank (~566)
  const int k_pad = (k + 127) & ~127;       // multiple of 128

  char* ws = (char*)d_ws;
  size_t off = 0;
  auto alloc = [&](size_t bytes) -> void* {
    void* p = ws + off;
    off += (bytes + 255) & ~(size_t)255;
    return p;
  };
  unsigned short* xb  = (unsigned short*)alloc((size_t)N * D_DIM * 2);
  unsigned short* Wt  = (unsigned short*)alloc((size_t)D_DIM * D_DIM * 2);
  unsigned short* Ukt = (unsigned short*)alloc((size_t)k_pad * D_DIM * 2);
  unsigned short* Vb  = (unsigned short*)alloc((size_t)D_DIM * k_pad * 2);
  unsigned short* A2  = (unsigned short*)alloc((size_t)N * k_pad * 2);
  float*          u1  = (float*)alloc((size_t)D_DIM * 4);
  float*          g8  = (float*)alloc((size_t)N * E_DIM * 4);
  if (off > ws_size) return;

  // 1) conversions + tiny routing precompute
  k_cvt_bf16<<<2048, 256, 0, stream>>>(x, xb, (long long)N * D_DIM);
  k_transpose_bf16<<<dim3(D_DIM / 32, D_DIM / 32), dim3(32, 8), 0, stream>>>(
      W, D_DIM, D_DIM, D_DIM, Wt, D_DIM);
  k_transpose_bf16<<<dim3(k_pad / 32, D_DIM / 32), dim3(32, 8), 0, stream>>>(
      U, D_DIM, k, k, Ukt, k_pad);
  k_pad_bf16<<<512, 256, 0, stream>>>(V, Vb, D_DIM, k, k_pad);
  k_u1<<<D_DIM / 4, 256, 0, stream>>>(U, Wg1, u1, D_DIM, k);

  // 2) gates: g8[N][8] = softmax((xb.u1) * Wg2)   (sum(g)=1 -> no rowscale)
  k_gate<<<N / 4, 256, 0, stream>>>(xb, u1, Wg2, g8, N);

  // 3) xu GEMM with fused routing epilogue -> A2 = bf16((xb@Ukt^T) * (g8@lam))
  k_gemm128<<<dim3(N / 128, k_pad / 128), 256, 0, stream>>>(
      xb, D_DIM, Ukt, D_DIM, D_DIM, g8, lam, k, A2, k_pad);

  // 4) fused GEMM: out = (xb@Wt^T + A2@Vb^T) * (1+v)
  const int gridM = N / 256;                 // 64
  const int gridN = D_DIM / 256;             // 8
  k_gemm256<1><<<gridM * gridN, 512, 0, stream>>>(
      xb, D_DIM, A2, k_pad,
      Wt, D_DIM, Vb, k_pad,
      D_DIM, D_DIM + k_pad, gridM,
      out, D_DIM, v);
}

// Round 9
// 326.563 us; speedup vs baseline: 1.5066x; 1.0038x over previous
//
#include <hip/hip_runtime.h>
#include <hip/hip_bf16.h>

#define D_DIM 2048
#define E_DIM 8

typedef __attribute__((ext_vector_type(8))) short short8;
typedef __attribute__((ext_vector_type(4))) float f32x4;
typedef __attribute__((ext_vector_type(16))) float f32x16;

__device__ __forceinline__ unsigned short f2bf(float f) {
  union { float f; unsigned int u; } v; v.f = f;
  unsigned int u = v.u;
  u += 0x7FFFu + ((u >> 16) & 1u);   // round-to-nearest-even
  return (unsigned short)(u >> 16);
}

__device__ __forceinline__ void async_copy16(const void* g, void* l) {
  __builtin_amdgcn_global_load_lds((const __attribute__((address_space(1))) void*)g,
                                   (__attribute__((address_space(3))) void*)l,
                                   16, 0, 0);
}

// ---------------- transpose f32 -> bf16 (with zero pad) ----------------
__global__ void k_transpose_bf16(const float* __restrict__ in, int in_rows, int in_cols,
                                 int in_ld, unsigned short* __restrict__ out, int out_rows) {
  __shared__ float tile[32][33];
  const int tx = threadIdx.x;  // 0..31
  const int ty = threadIdx.y;  // 0..7
  const int c = blockIdx.x * 32 + tx;
  #pragma unroll
  for (int i = 0; i < 4; ++i) {
    const int r = blockIdx.y * 32 + ty + i * 8;
    float vv = 0.0f;
    if (r < in_rows && c < in_cols) vv = in[(size_t)r * in_ld + c];
    tile[ty + i * 8][tx] = vv;
  }
  __syncthreads();
  const int oc = blockIdx.y * 32 + tx;   // = original row
  #pragma unroll
  for (int i = 0; i < 4; ++i) {
    const int orow = blockIdx.x * 32 + ty + i * 8;  // = original col (padded)
    if (orow < out_rows && oc < in_rows)
      out[(size_t)orow * in_rows + oc] = f2bf(tile[tx][ty + i * 8]);
  }
}

// ---------------- pad-copy f32 -> bf16 (row-major, pad cols with 0) ----------------
__global__ void k_pad_bf16(const float* __restrict__ in, unsigned short* __restrict__ out,
                           int rows, int cols, int cols_pad) {
  long long idx = (long long)blockIdx.x * blockDim.x + threadIdx.x;
  const long long total = (long long)rows * cols_pad;
  const long long stride = (long long)gridDim.x * blockDim.x;
  for (; idx < total; idx += stride) {
    const int r = (int)(idx / cols_pad);
    const int c = (int)(idx % cols_pad);
    out[idx] = (c < cols) ? f2bf(in[(size_t)r * cols + c]) : (unsigned short)0;
  }
}

// ---------------- u1 = U @ Wg1  (f32, one wave per output row d) ----------------
__global__ void k_u1(const float* __restrict__ U, const float* __restrict__ Wg1,
                     float* __restrict__ u1, int D, int k) {
  const int w = threadIdx.x >> 6;
  const int lane = threadIdx.x & 63;
  const int d = blockIdx.x * 4 + w;
  if (d >= D) return;
  const float* row = U + (size_t)d * k;
  float s = 0.0f;
  for (int j = lane; j < k; j += 64) s += row[j] * Wg1[j];
  #pragma unroll
  for (int off = 32; off; off >>= 1) s += __shfl_xor(s, off);
  if (lane == 0) u1[d] = s;
}

// ---------------- fused cvt+gate: xb = bf16(x); g8 = softmax((x.u1)*Wg2) ----------
__global__ void k_cvtgate(const float* __restrict__ x,
                          unsigned short* __restrict__ xb,
                          const float* __restrict__ u1, const float* __restrict__ Wg2,
                          float* __restrict__ g8, int Nrows) {
  const int w = threadIdx.x >> 6;
  const int lane = threadIdx.x & 63;
  const int row = blockIdx.x * 4 + w;
  if (row >= Nrows) return;
  const float* xr = x + (size_t)row * D_DIM;
  unsigned short* xo = xb + (size_t)row * D_DIM;
  float s = 0.0f;
  #pragma unroll
  for (int t = 0; t < D_DIM / 512; ++t) {
    const int base = (t * 64 + lane) * 8;
    float4 a = *(const float4*)(xr + base);
    float4 b = *(const float4*)(xr + base + 4);
    float4 ua = *(const float4*)(u1 + base);
    float4 ub = *(const float4*)(u1 + base + 4);
    s += a.x * ua.x + a.y * ua.y + a.z * ua.z + a.w * ua.w +
         b.x * ub.x + b.y * ub.y + b.z * ub.z + b.w * ub.w;
    short8 r;
    r[0] = (short)f2bf(a.x); r[1] = (short)f2bf(a.y);
    r[2] = (short)f2bf(a.z); r[3] = (short)f2bf(a.w);
    r[4] = (short)f2bf(b.x); r[5] = (short)f2bf(b.y);
    r[6] = (short)f2bf(b.z); r[7] = (short)f2bf(b.w);
    *(short8*)(xo + base) = r;
  }
  #pragma unroll
  for (int off = 32; off; off >>= 1) s += __shfl_xor(s, off);
  if (lane == 0) {
    float lg[E_DIM], mx = -INFINITY;
    #pragma unroll
    for (int e = 0; e < E_DIM; ++e) { lg[e] = s * Wg2[e]; mx = fmaxf(mx, lg[e]); }
    float Z = 0.0f;
    #pragma unroll
    for (int e = 0; e < E_DIM; ++e) { lg[e] = expf(lg[e] - mx); Z += lg[e]; }
    const float inv = 1.0f / Z;
    #pragma unroll
    for (int e = 0; e < E_DIM; ++e) g8[(size_t)row * E_DIM + e] = lg[e] * inv;
  }
}

// ---------------- 128x128 4-wave, 2-slot dbuf, 3 blocks/CU, A2-fused epilogue ------
__global__ __launch_bounds__(256, 3) void k_gemm128(
    const unsigned short* __restrict__ A, long long lda,
    const unsigned short* __restrict__ B, long long ldb,
    int Ktot,
    const float* __restrict__ g8, const float* __restrict__ lam, int k_real,
    unsigned short* __restrict__ A2, int lda2) {
  __shared__ unsigned short lds[2 * 8192];   // 32 KiB: slot = A[128][32] + B[128][32]
  const int tid = threadIdx.x;
  const int lane = tid & 63;
  const int w = tid >> 6;            // 0..3
  const long long brow = (long long)blockIdx.x * 128;
  const long long bcol = (long long)blockIdx.y * 128;
  const int c0 = w * 2;
  const int sr0 = lane >> 2;
  const int sj  = lane & 3;
  const int l15 = lane & 15;
  const int jhi = lane >> 4;
  const int wr = (w >> 1) * 64;
  const int wc = (w & 1) * 64;

  auto stage = [&](int tt) {
    unsigned short* dstA = lds + (tt & 1) * 8192;
    #pragma unroll
    for (int c = 0; c < 2; ++c) {
      const int chunk = c0 + c;
      const int lrow = chunk * 16 + sr0;
      const int jj = sj ^ ((lrow >> 1) & 3);
      async_copy16(A + (brow + lrow) * lda + (long long)tt * 32 + jj * 8,
                   (void*)(dstA + chunk * 512));
      async_copy16(B + (bcol + lrow) * ldb + (long long)tt * 32 + jj * 8,
                   (void*)(dstA + 4096 + chunk * 512));
    }
  };

  f32x4 acc[4][4];
  #pragma unroll
  for (int m = 0; m < 4; ++m)
    #pragma unroll
    for (int n = 0; n < 4; ++n)
      #pragma unroll
      for (int j = 0; j < 4; ++j) acc[m][n][j] = 0.0f;

  const int NT = Ktot >> 5;
  stage(0);
  asm volatile("s_waitcnt vmcnt(0)" ::: "memory");
  __builtin_amdgcn_s_barrier();

  for (int t = 0; t < NT; ++t) {
    const unsigned short* Areg = lds + (t & 1) * 8192;
    const unsigned short* Breg = Areg + 4096;
    if (t + 1 < NT) stage(t + 1);
    short8 av[4], bv[4];
    #pragma unroll
    for (int m = 0; m < 4; ++m) {
      const int row = wr + m * 16 + l15;
      const int jj = jhi ^ ((row >> 1) & 3);
      av[m] = *(const short8*)(Areg + row * 32 + jj * 8);
    }
    #pragma unroll
    for (int n = 0; n < 4; ++n) {
      const int row = wc + n * 16 + l15;
      const int jj = jhi ^ ((row >> 1) & 3);
      bv[n] = *(const short8*)(Breg + row * 32 + jj * 8);
    }
    __builtin_amdgcn_s_setprio(1);
    #pragma unroll
    for (int m = 0; m < 4; ++m)
      #pragma unroll
      for (int n = 0; n < 4; ++n)
        acc[m][n] = __builtin_amdgcn_mfma_f32_16x16x32_bf16(av[m], bv[n], acc[m][n], 0, 0, 0);
    __builtin_amdgcn_s_setprio(0);
    asm volatile("s_waitcnt vmcnt(0)" ::: "memory");
    __builtin_amdgcn_s_barrier();
  }

  // epilogue: A2 = bf16(acc * coef), coef = sum_e g8[row,e]*lam[e,col]
  float lamE[E_DIM][4];
  #pragma unroll
  for (int n = 0; n < 4; ++n) {
    const long long col = bcol + wc + n * 16 + l15;
    #pragma unroll
    for (int e = 0; e < E_DIM; ++e)
      lamE[e][n] = (col < k_real) ? lam[(size_t)e * k_real + col] : 0.0f;
  }
  #pragma unroll
  for (int m = 0; m < 4; ++m) {
    float coef[4][4];   // [j][n]
    #pragma unroll
    for (int j = 0; j < 4; ++j)
      #pragma unroll
      for (int n = 0; n < 4; ++n) coef[j][n] = 0.0f;
    #pragma unroll
    for (int j = 0; j < 4; ++j) {
      const long long row = brow + wr + m * 16 + jhi * 4 + j;
      const float* gr = g8 + row * E_DIM;
      #pragma unroll
      for (int e = 0; e < E_DIM; ++e) {
        const float ge = gr[e];
        #pragma unroll
        for (int n = 0; n < 4; ++n) coef[j][n] += ge * lamE[e][n];
      }
    }
    #pragma unroll
    for (int n = 0; n < 4; ++n) {
      const long long col = bcol + wc + n * 16 + l15;
      #pragma unroll
      for (int j = 0; j < 4; ++j) {
        const long long row = brow + wr + m * 16 + jhi * 4 + j;
        A2[row * lda2 + col] = f2bf(acc[m][n][j] * coef[j][n]);
      }
    }
  }
}

// ---------------- 256x256 8-wave, 4-slot rotation, reg-dbuf, 32x32x16 MFMA ---------
// A-frag (32x32x16): lane l holds A[l&31][(l>>5)*8 + i]  (extends verified 16x16 pattern)
// C/D: col = lane&31, row = (reg&3) + 8*(reg>>2) + 4*(lane>>5)   [m74/m101-verified]
template<int EPI>
__global__ __launch_bounds__(512, 2) void k_gemm256(
    const unsigned short* __restrict__ A0, int lda0,
    const unsigned short* __restrict__ A1, int lda1,
    const unsigned short* __restrict__ B0, int ldb0,
    const unsigned short* __restrict__ B1, int ldb1,
    int ka0, int Ktot, int gridM,
    float* __restrict__ Cout, int ldc,
    const float* __restrict__ vcol) {
  __shared__ unsigned short lds[4 * 16384];   // 128 KiB
  const int tid = threadIdx.x;
  const int lane = tid & 63;
  const int w = tid >> 6;            // 0..7
  const int wm = w >> 2;             // 0..1  (M half)
  const int wn = w & 3;              // 0..3  (N quarter)

  // bijective XCD swizzle (grid size divisible by 8)
  int bid = blockIdx.x;
  const int cpx = gridDim.x >> 3;
  bid = (bid & 7) * cpx + (bid >> 3);
  const int bx = bid % gridM;
  const int by = bid / gridM;
  const long long brow = (long long)bx * 256;
  const long long bcol = (long long)by * 256;

  const int c0 = w * 2;
  const int sr0 = lane >> 2;
  const int sj  = lane & 3;
  const int r31 = lane & 31;
  const int khalf = lane >> 5;

  auto stage = [&](int tt) {
    const int k0 = tt * 32;
    const unsigned short* PA; long long ldA; long long kA;
    const unsigned short* PB; long long ldB; long long kB;
    if (k0 < ka0) { PA = A0; ldA = lda0; kA = k0;       PB = B0; ldB = ldb0; kB = k0; }
    else          { PA = A1; ldA = lda1; kA = k0 - ka0; PB = B1; ldB = ldb1; kB = k0 - ka0; }
    unsigned short* dst = lds + (tt & 3) * 16384;
    #pragma unroll
    for (int c = 0; c < 2; ++c) {
      const int chunk = c0 + c;
      const int lrow = chunk * 16 + sr0;
      const int jj = sj ^ ((lrow >> 1) & 3);
      async_copy16(PA + (brow + lrow) * ldA + kA + jj * 8, (void*)(dst + chunk * 512));
      async_copy16(PB + (bcol + lrow) * ldB + kB + jj * 8, (void*)(dst + 8192 + chunk * 512));
    }
  };

  // av[mm*2+k2], bv[nn*2+k2]: global k-slot gs = k2*2 + khalf, LDS slot = gs^swz(row)
  auto load_frags = [&](int tt, short8* av, short8* bv) {
    const unsigned short* Areg = lds + (tt & 3) * 16384;
    const unsigned short* Breg = Areg + 8192;
    #pragma unroll
    for (int mm = 0; mm < 4; ++mm) {
      const int row = wm * 128 + mm * 32 + r31;
      const int swz = (row >> 1) & 3;
      #pragma unroll
      for (int k2 = 0; k2 < 2; ++k2) {
        const int gs = k2 * 2 + khalf;
        av[mm * 2 + k2] = *(const short8*)(Areg + row * 32 + (gs ^ swz) * 8);
      }
    }
    #pragma unroll
    for (int nn = 0; nn < 2; ++nn) {
      const int row = wn * 64 + nn * 32 + r31;
      const int swz = (row >> 1) & 3;
      #pragma unroll
      for (int k2 = 0; k2 < 2; ++k2) {
        const int gs = k2 * 2 + khalf;
        bv[nn * 2 + k2] = *(const short8*)(Breg + row * 32 + (gs ^ swz) * 8);
      }
    }
  };

  f32x16 acc[4][2];
  #pragma unroll
  for (int mm = 0; mm < 4; ++mm)
    #pragma unroll
    for (int nn = 0; nn < 2; ++nn)
      #pragma unroll
      for (int q = 0; q < 16; ++q) acc[mm][nn][q] = 0.0f;

  auto do_mfma = [&](short8* av, short8* bv) {
    __builtin_amdgcn_s_setprio(1);
    #pragma unroll
    for (int mm = 0; mm < 4; ++mm)
      #pragma unroll
      for (int nn = 0; nn < 2; ++nn)
        #pragma unroll
        for (int k2 = 0; k2 < 2; ++k2)
          acc[mm][nn] = __builtin_amdgcn_mfma_f32_32x32x16_bf16(
              av[mm * 2 + k2], bv[nn * 2 + k2], acc[mm][nn], 0, 0, 0);
    __builtin_amdgcn_s_setprio(0);
  };

  const int NT = Ktot >> 5;   // even (Ktot multiple of 64)
  stage(0); stage(1); stage(2);
  asm volatile("s_waitcnt vmcnt(4)" ::: "memory");   // tiles 0,1 landed
  __builtin_amdgcn_s_barrier();

  short8 avA[8], bvA[4], avB[8], bvB[4];
  load_frags(0, avA, bvA);

  for (int t = 0; t < NT; t += 2) {
    // body t: compute set A, read tile t+1 into set B
    if (t + 3 < NT) stage(t + 3);
    load_frags(t + 1, avB, bvB);
    do_mfma(avA, bvA);
    asm volatile("s_waitcnt vmcnt(4)" ::: "memory");
    __builtin_amdgcn_s_barrier();
    // body t+1: compute set B, read tile t+2 into set A
    if (t + 4 < NT) stage(t + 4);
    if (t + 2 < NT) load_frags(t + 2, avA, bvA);
    do_mfma(avB, bvB);
    asm volatile("s_waitcnt vmcnt(4)" ::: "memory");
    __builtin_amdgcn_s_barrier();
  }

  // epilogue: 32x32 C/D layout; out *= (1+v[col])
  #pragma unroll
  for (int mm = 0; mm < 4; ++mm) {
    #pragma unroll
    for (int nn = 0; nn < 2; ++nn) {
      const long long col = bcol + wn * 64 + nn * 32 + r31;
      float cs = 1.0f;
      if (EPI == 1) cs = 1.0f + vcol[col];
      #pragma unroll
      for (int q = 0; q < 16; ++q) {
        const long long row = brow + wm * 128 + mm * 32 + (q & 3) + 8 * (q >> 2) + 4 * khalf;
        Cout[row * ldc + col] = acc[mm][nn][q] * cs;
      }
    }
  }
}

extern "C" void kernel_launch(void* const* d_in, const int* in_sizes, int n_in,
                              void* d_out, int out_size, void* d_ws, size_t ws_size,
                              hipStream_t stream) {
  const float* x   = (const float*)d_in[0];
  const float* W   = (const float*)d_in[1];
  const float* U   = (const float*)d_in[2];
  const float* V   = (const float*)d_in[3];
  const float* lam = (const float*)d_in[4];
  const float* v   = (const float*)d_in[5];
  const float* Wg1 = (const float*)d_in[6];
  const float* Wg2 = (const float*)d_in[7];
  float* out = (float*)d_out;

  const int N = in_sizes[0] / D_DIM;        // 16384
  const int k = in_sizes[2] / D_DIM;        // SVD rank (~566)
  const int k_pad = (k + 127) & ~127;       // multiple of 128

  char* ws = (char*)d_ws;
  size_t off = 0;
  auto alloc = [&](size_t bytes) -> void* {
    void* p = ws + off;
    off += (bytes + 255) & ~(size_t)255;
    return p;
  };
  unsigned short* xb  = (unsigned short*)alloc((size_t)N * D_DIM * 2);
  unsigned short* Wt  = (unsigned short*)alloc((size_t)D_DIM * D_DIM * 2);
  unsigned short* Ukt = (unsigned short*)alloc((size_t)k_pad * D_DIM * 2);
  unsigned short* Vb  = (unsigned short*)alloc((size_t)D_DIM * k_pad * 2);
  unsigned short* A2  = (unsigned short*)alloc((size_t)N * k_pad * 2);
  float*          u1  = (float*)alloc((size_t)D_DIM * 4);
  float*          g8  = (float*)alloc((size_t)N * E_DIM * 4);
  if (off > ws_size) return;

  // 1) tiny routing precompute, then fused convert+gate
  k_u1<<<D_DIM / 4, 256, 0, stream>>>(U, Wg1, u1, D_DIM, k);
  k_cvtgate<<<N / 4, 256, 0, stream>>>(x, xb, u1, Wg2, g8, N);
  k_transpose_bf16<<<dim3(D_DIM / 32, D_DIM / 32), dim3(32, 8), 0, stream>>>(
      W, D_DIM, D_DIM, D_DIM, Wt, D_DIM);
  k_transpose_bf16<<<dim3(k_pad / 32, D_DIM / 32), dim3(32, 8), 0, stream>>>(
      U, D_DIM, k, k, Ukt, k_pad);
  k_pad_bf16<<<512, 256, 0, stream>>>(V, Vb, D_DIM, k, k_pad);

  // 2) xu GEMM with fused routing epilogue -> A2 = bf16((xb@Ukt^T) * (g8@lam))
  k_gemm128<<<dim3(N / 128, k_pad / 128), 256, 0, stream>>>(
      xb, D_DIM, Ukt, D_DIM, D_DIM, g8, lam, k, A2, k_pad);

  // 3) fused GEMM: out = (xb@Wt^T + A2@Vb^T) * (1+v)   [32x32x16 MFMA]
  const int gridM = N / 256;                 // 64
  const int gridN = D_DIM / 256;             // 8
  k_gemm256<1><<<gridM * gridN, 512, 0, stream>>>(
      xb, D_DIM, A2, k_pad,
      Wt, D_DIM, Vb, k_pad,
      D_DIM, D_DIM + k_pad, gridM,
      out, D_DIM, v);
}

// Round 10
// 311.144 us; speedup vs baseline: 1.5813x; 1.0496x over previous
//
#include <hip/hip_runtime.h>
#include <hip/hip_bf16.h>

#define D_DIM 2048
#define E_DIM 8

typedef __attribute__((ext_vector_type(8))) short short8;
typedef __attribute__((ext_vector_type(4))) float f32x4;

__device__ __forceinline__ unsigned short f2bf(float f) {
  union { float f; unsigned int u; } v; v.f = f;
  unsigned int u = v.u;
  u += 0x7FFFu + ((u >> 16) & 1u);   // round-to-nearest-even
  return (unsigned short)(u >> 16);
}

__device__ __forceinline__ void async_copy16(const void* g, void* l) {
  __builtin_amdgcn_global_load_lds((const __attribute__((address_space(1))) void*)g,
                                   (__attribute__((address_space(3))) void*)l,
                                   16, 0, 0);
}

// ---------------- transpose f32 -> bf16 (with zero pad) ----------------
__global__ void k_transpose_bf16(const float* __restrict__ in, int in_rows, int in_cols,
                                 int in_ld, unsigned short* __restrict__ out, int out_rows) {
  __shared__ float tile[32][33];
  const int tx = threadIdx.x;  // 0..31
  const int ty = threadIdx.y;  // 0..7
  const int c = blockIdx.x * 32 + tx;
  #pragma unroll
  for (int i = 0; i < 4; ++i) {
    const int r = blockIdx.y * 32 + ty + i * 8;
    float vv = 0.0f;
    if (r < in_rows && c < in_cols) vv = in[(size_t)r * in_ld + c];
    tile[ty + i * 8][tx] = vv;
  }
  __syncthreads();
  const int oc = blockIdx.y * 32 + tx;   // = original row
  #pragma unroll
  for (int i = 0; i < 4; ++i) {
    const int orow = blockIdx.x * 32 + ty + i * 8;  // = original col (padded)
    if (orow < out_rows && oc < in_rows)
      out[(size_t)orow * in_rows + oc] = f2bf(tile[tx][ty + i * 8]);
  }
}

// ---------------- pad-copy f32 -> bf16 (row-major, pad cols with 0) ----------------
__global__ void k_pad_bf16(const float* __restrict__ in, unsigned short* __restrict__ out,
                           int rows, int cols, int cols_pad) {
  long long idx = (long long)blockIdx.x * blockDim.x + threadIdx.x;
  const long long total = (long long)rows * cols_pad;
  const long long stride = (long long)gridDim.x * blockDim.x;
  for (; idx < total; idx += stride) {
    const int r = (int)(idx / cols_pad);
    const int c = (int)(idx % cols_pad);
    out[idx] = (c < cols) ? f2bf(in[(size_t)r * cols + c]) : (unsigned short)0;
  }
}

// ---------------- u1 = U @ Wg1  (f32, one wave per output row d) ----------------
__global__ void k_u1(const float* __restrict__ U, const float* __restrict__ Wg1,
                     float* __restrict__ u1, int D, int k) {
  const int w = threadIdx.x >> 6;
  const int lane = threadIdx.x & 63;
  const int d = blockIdx.x * 4 + w;
  if (d >= D) return;
  const float* row = U + (size_t)d * k;
  float s = 0.0f;
  for (int j = lane; j < k; j += 64) s += row[j] * Wg1[j];
  #pragma unroll
  for (int off = 32; off; off >>= 1) s += __shfl_xor(s, off);
  if (lane == 0) u1[d] = s;
}

// ---------------- fused cvt+gate: xb = bf16(x); g8 = softmax((x.u1)*Wg2) ----------
__global__ void k_cvtgate(const float* __restrict__ x,
                          unsigned short* __restrict__ xb,
                          const float* __restrict__ u1, const float* __restrict__ Wg2,
                          float* __restrict__ g8, int Nrows) {
  const int w = threadIdx.x >> 6;
  const int lane = threadIdx.x & 63;
  const int row = blockIdx.x * 4 + w;
  if (row >= Nrows) return;
  const float* xr = x + (size_t)row * D_DIM;
  unsigned short* xo = xb + (size_t)row * D_DIM;
  float s = 0.0f;
  #pragma unroll
  for (int t = 0; t < D_DIM / 512; ++t) {
    const int base = (t * 64 + lane) * 8;
    float4 a = *(const float4*)(xr + base);
    float4 b = *(const float4*)(xr + base + 4);
    float4 ua = *(const float4*)(u1 + base);
    float4 ub = *(const float4*)(u1 + base + 4);
    s += a.x * ua.x + a.y * ua.y + a.z * ua.z + a.w * ua.w +
         b.x * ub.x + b.y * ub.y + b.z * ub.z + b.w * ub.w;
    short8 r;
    r[0] = (short)f2bf(a.x); r[1] = (short)f2bf(a.y);
    r[2] = (short)f2bf(a.z); r[3] = (short)f2bf(a.w);
    r[4] = (short)f2bf(b.x); r[5] = (short)f2bf(b.y);
    r[6] = (short)f2bf(b.z); r[7] = (short)f2bf(b.w);
    *(short8*)(xo + base) = r;
  }
  #pragma unroll
  for (int off = 32; off; off >>= 1) s += __shfl_xor(s, off);
  if (lane == 0) {
    float lg[E_DIM], mx = -INFINITY;
    #pragma unroll
    for (int e = 0; e < E_DIM; ++e) { lg[e] = s * Wg2[e]; mx = fmaxf(mx, lg[e]); }
    float Z = 0.0f;
    #pragma unroll
    for (int e = 0; e < E_DIM; ++e) { lg[e] = expf(lg[e] - mx); Z += lg[e]; }
    const float inv = 1.0f / Z;
    #pragma unroll
    for (int e = 0; e < E_DIM; ++e) g8[(size_t)row * E_DIM + e] = lg[e] * inv;
  }
}

// ---------------- 128x128 4-wave, 2-slot dbuf, 3 blocks/CU, A2-fused epilogue ------
__global__ __launch_bounds__(256, 3) void k_gemm128(
    const unsigned short* __restrict__ A, long long lda,
    const unsigned short* __restrict__ B, long long ldb,
    int Ktot,
    const float* __restrict__ g8, const float* __restrict__ lam, int k_real,
    unsigned short* __restrict__ A2, int lda2) {
  __shared__ unsigned short lds[2 * 8192];   // 32 KiB: slot = A[128][32] + B[128][32]
  const int tid = threadIdx.x;
  const int lane = tid & 63;
  const int w = tid >> 6;            // 0..3
  const long long brow = (long long)blockIdx.x * 128;
  const long long bcol = (long long)blockIdx.y * 128;
  const int c0 = w * 2;
  const int sr0 = lane >> 2;
  const int sj  = lane & 3;
  const int l15 = lane & 15;
  const int jhi = lane >> 4;
  const int wr = (w >> 1) * 64;
  const int wc = (w & 1) * 64;

  auto stage = [&](int tt) {
    unsigned short* dstA = lds + (tt & 1) * 8192;
    #pragma unroll
    for (int c = 0; c < 2; ++c) {
      const int chunk = c0 + c;
      const int lrow = chunk * 16 + sr0;
      const int jj = sj ^ ((lrow >> 1) & 3);
      async_copy16(A + (brow + lrow) * lda + (long long)tt * 32 + jj * 8,
                   (void*)(dstA + chunk * 512));
      async_copy16(B + (bcol + lrow) * ldb + (long long)tt * 32 + jj * 8,
                   (void*)(dstA + 4096 + chunk * 512));
    }
  };

  f32x4 acc[4][4];
  #pragma unroll
  for (int m = 0; m < 4; ++m)
    #pragma unroll
    for (int n = 0; n < 4; ++n)
      #pragma unroll
      for (int j = 0; j < 4; ++j) acc[m][n][j] = 0.0f;

  const int NT = Ktot >> 5;
  stage(0);
  asm volatile("s_waitcnt vmcnt(0)" ::: "memory");
  __builtin_amdgcn_s_barrier();

  for (int t = 0; t < NT; ++t) {
    const unsigned short* Areg = lds + (t & 1) * 8192;
    const unsigned short* Breg = Areg + 4096;
    if (t + 1 < NT) stage(t + 1);
    short8 av[4], bv[4];
    #pragma unroll
    for (int m = 0; m < 4; ++m) {
      const int row = wr + m * 16 + l15;
      const int jj = jhi ^ ((row >> 1) & 3);
      av[m] = *(const short8*)(Areg + row * 32 + jj * 8);
    }
    #pragma unroll
    for (int n = 0; n < 4; ++n) {
      const int row = wc + n * 16 + l15;
      const int jj = jhi ^ ((row >> 1) & 3);
      bv[n] = *(const short8*)(Breg + row * 32 + jj * 8);
    }
    __builtin_amdgcn_s_setprio(1);
    #pragma unroll
    for (int m = 0; m < 4; ++m)
      #pragma unroll
      for (int n = 0; n < 4; ++n)
        acc[m][n] = __builtin_amdgcn_mfma_f32_16x16x32_bf16(av[m], bv[n], acc[m][n], 0, 0, 0);
    __builtin_amdgcn_s_setprio(0);
    asm volatile("s_waitcnt vmcnt(0)" ::: "memory");
    __builtin_amdgcn_s_barrier();
  }

  // epilogue: A2 = bf16(acc * coef), coef = sum_e g8[row,e]*lam[e,col]
  float lamE[E_DIM][4];
  #pragma unroll
  for (int n = 0; n < 4; ++n) {
    const long long col = bcol + wc + n * 16 + l15;
    #pragma unroll
    for (int e = 0; e < E_DIM; ++e)
      lamE[e][n] = (col < k_real) ? lam[(size_t)e * k_real + col] : 0.0f;
  }
  #pragma unroll
  for (int m = 0; m < 4; ++m) {
    float coef[4][4];   // [j][n]
    #pragma unroll
    for (int j = 0; j < 4; ++j)
      #pragma unroll
      for (int n = 0; n < 4; ++n) coef[j][n] = 0.0f;
    #pragma unroll
    for (int j = 0; j < 4; ++j) {
      const long long row = brow + wr + m * 16 + jhi * 4 + j;
      const float* gr = g8 + row * E_DIM;
      #pragma unroll
      for (int e = 0; e < E_DIM; ++e) {
        const float ge = gr[e];
        #pragma unroll
        for (int n = 0; n < 4; ++n) coef[j][n] += ge * lamE[e][n];
      }
    }
    #pragma unroll
    for (int n = 0; n < 4; ++n) {
      const long long col = bcol + wc + n * 16 + l15;
      #pragma unroll
      for (int j = 0; j < 4; ++j) {
        const long long row = brow + wr + m * 16 + jhi * 4 + j;
        A2[row * lda2 + col] = f2bf(acc[m][n][j] * coef[j][n]);
      }
    }
  }
}

// ---------------- 256x256 8-wave, 4-slot rotation, reg-double-buffered (R4/R8 best) ----
template<int EPI>
__global__ __launch_bounds__(512, 2) void k_gemm256(
    const unsigned short* __restrict__ A0, int lda0,
    const unsigned short* __restrict__ A1, int lda1,
    const unsigned short* __restrict__ B0, int ldb0,
    const unsigned short* __restrict__ B1, int ldb1,
    int ka0, int Ktot, int gridM,
    float* __restrict__ Cout, int ldc,
    const float* __restrict__ vcol) {
  __shared__ unsigned short lds[4 * 16384];   // 128 KiB
  const int tid = threadIdx.x;
  const int lane = tid & 63;
  const int w = tid >> 6;            // 0..7
  const int wm = w >> 2;             // 0..1  (M half)
  const int wn = w & 3;              // 0..3  (N quarter)

  // bijective XCD swizzle (grid size divisible by 8)
  int bid = blockIdx.x;
  const int cpx = gridDim.x >> 3;
  bid = (bid & 7) * cpx + (bid >> 3);
  const int bx = bid % gridM;
  const int by = bid / gridM;
  const long long brow = (long long)bx * 256;
  const long long bcol = (long long)by * 256;

  const int c0 = w * 2;
  const int sr0 = lane >> 2;
  const int sj  = lane & 3;
  const int l15 = lane & 15;
  const int jhi = lane >> 4;

  auto stage = [&](int tt) {
    const int k0 = tt * 32;
    const unsigned short* PA; long long ldA; long long kA;
    const unsigned short* PB; long long ldB; long long kB;
    if (k0 < ka0) { PA = A0; ldA = lda0; kA = k0;       PB = B0; ldB = ldb0; kB = k0; }
    else          { PA = A1; ldA = lda1; kA = k0 - ka0; PB = B1; ldB = ldb1; kB = k0 - ka0; }
    unsigned short* dst = lds + (tt & 3) * 16384;
    #pragma unroll
    for (int c = 0; c < 2; ++c) {
      const int chunk = c0 + c;
      const int lrow = chunk * 16 + sr0;
      const int jj = sj ^ ((lrow >> 1) & 3);
      async_copy16(PA + (brow + lrow) * ldA + kA + jj * 8, (void*)(dst + chunk * 512));
      async_copy16(PB + (bcol + lrow) * ldB + kB + jj * 8, (void*)(dst + 8192 + chunk * 512));
    }
  };

  auto load_frags = [&](int tt, short8* av, short8* bv) {
    const unsigned short* Areg = lds + (tt & 3) * 16384;
    const unsigned short* Breg = Areg + 8192;
    #pragma unroll
    for (int m = 0; m < 8; ++m) {
      const int row = wm * 128 + m * 16 + l15;
      const int jj = jhi ^ ((row >> 1) & 3);
      av[m] = *(const short8*)(Areg + row * 32 + jj * 8);
    }
    #pragma unroll
    for (int n = 0; n < 4; ++n) {
      const int row = wn * 64 + n * 16 + l15;
      const int jj = jhi ^ ((row >> 1) & 3);
      bv[n] = *(const short8*)(Breg + row * 32 + jj * 8);
    }
  };

  f32x4 acc[8][4];
  #pragma unroll
  for (int m = 0; m < 8; ++m)
    #pragma unroll
    for (int n = 0; n < 4; ++n)
      #pragma unroll
      for (int j = 0; j < 4; ++j) acc[m][n][j] = 0.0f;

  auto do_mfma = [&](short8* av, short8* bv) {
    __builtin_amdgcn_s_setprio(1);
    #pragma unroll
    for (int m = 0; m < 8; ++m)
      #pragma unroll
      for (int n = 0; n < 4; ++n)
        acc[m][n] = __builtin_amdgcn_mfma_f32_16x16x32_bf16(av[m], bv[n], acc[m][n], 0, 0, 0);
    __builtin_amdgcn_s_setprio(0);
  };

  const int NT = Ktot >> 5;   // even (Ktot multiple of 64)
  stage(0); stage(1); stage(2);
  asm volatile("s_waitcnt vmcnt(4)" ::: "memory");   // tiles 0,1 landed
  __builtin_amdgcn_s_barrier();

  short8 avA[8], bvA[4], avB[8], bvB[4];
  load_frags(0, avA, bvA);

  for (int t = 0; t < NT; t += 2) {
    // body t: compute set A, read tile t+1 into set B
    if (t + 3 < NT) stage(t + 3);
    load_frags(t + 1, avB, bvB);
    do_mfma(avA, bvA);
    asm volatile("s_waitcnt vmcnt(4)" ::: "memory");
    __builtin_amdgcn_s_barrier();
    // body t+1: compute set B, read tile t+2 into set A
    if (t + 4 < NT) stage(t + 4);
    if (t + 2 < NT) load_frags(t + 2, avA, bvA);
    do_mfma(avB, bvB);
    asm volatile("s_waitcnt vmcnt(4)" ::: "memory");
    __builtin_amdgcn_s_barrier();
  }

  // epilogue: C/D layout col = lane&15, row = (lane>>4)*4 + j ; out *= (1+v[col])
  #pragma unroll
  for (int m = 0; m < 8; ++m) {
    #pragma unroll
    for (int n = 0; n < 4; ++n) {
      const long long col = bcol + wn * 64 + n * 16 + l15;
      float cs = 1.0f;
      if (EPI == 1) cs = 1.0f + vcol[col];
      #pragma unroll
      for (int j = 0; j < 4; ++j) {
        const long long row = brow + wm * 128 + m * 16 + jhi * 4 + j;
        Cout[row * ldc + col] = acc[m][n][j] * cs;
      }
    }
  }
}

extern "C" void kernel_launch(void* const* d_in, const int* in_sizes, int n_in,
                              void* d_out, int out_size, void* d_ws, size_t ws_size,
                              hipStream_t stream) {
  const float* x   = (const float*)d_in[0];
  const float* W   = (const float*)d_in[1];
  const float* U   = (const float*)d_in[2];
  const float* V   = (const float*)d_in[3];
  const float* lam = (const float*)d_in[4];
  const float* v   = (const float*)d_in[5];
  const float* Wg1 = (const float*)d_in[6];
  const float* Wg2 = (const float*)d_in[7];
  float* out = (float*)d_out;

  const int N = in_sizes[0] / D_DIM;        // 16384
  const int k = in_sizes[2] / D_DIM;        // SVD rank (~566)
  const int k_pad = (k + 127) & ~127;       // multiple of 128

  char* ws = (char*)d_ws;
  size_t off = 0;
  auto alloc = [&](size_t bytes) -> void* {
    void* p = ws + off;
    off += (bytes + 255) & ~(size_t)255;
    return p;
  };
  unsigned short* xb  = (unsigned short*)alloc((size_t)N * D_DIM * 2);
  unsigned short* Wt  = (unsigned short*)alloc((size_t)D_DIM * D_DIM * 2);
  unsigned short* Ukt = (unsigned short*)alloc((size_t)k_pad * D_DIM * 2);
  unsigned short* Vb  = (unsigned short*)alloc((size_t)D_DIM * k_pad * 2);
  unsigned short* A2  = (unsigned short*)alloc((size_t)N * k_pad * 2);
  float*          u1  = (float*)alloc((size_t)D_DIM * 4);
  float*          g8  = (float*)alloc((size_t)N * E_DIM * 4);
  if (off > ws_size) return;

  // 1) tiny routing precompute, then fused convert+gate
  k_u1<<<D_DIM / 4, 256, 0, stream>>>(U, Wg1, u1, D_DIM, k);
  k_cvtgate<<<N / 4, 256, 0, stream>>>(x, xb, u1, Wg2, g8, N);
  k_transpose_bf16<<<dim3(D_DIM / 32, D_DIM / 32), dim3(32, 8), 0, stream>>>(
      W, D_DIM, D_DIM, D_DIM, Wt, D_DIM);
  k_transpose_bf16<<<dim3(k_pad / 32, D_DIM / 32), dim3(32, 8), 0, stream>>>(
      U, D_DIM, k, k, Ukt, k_pad);
  k_pad_bf16<<<512, 256, 0, stream>>>(V, Vb, D_DIM, k, k_pad);

  // 2) xu GEMM with fused routing epilogue -> A2 = bf16((xb@Ukt^T) * (g8@lam))
  k_gemm128<<<dim3(N / 128, k_pad / 128), 256, 0, stream>>>(
      xb, D_DIM, Ukt, D_DIM, D_DIM, g8, lam, k, A2, k_pad);

  // 3) fused GEMM: out = (xb@Wt^T + A2@Vb^T) * (1+v)   [16x16x32 MFMA, R8 body]
  const int gridM = N / 256;                 // 64
  const int gridN = D_DIM / 256;             // 8
  k_gemm256<1><<<gridM * gridN, 512, 0, stream>>>(
      xb, D_DIM, A2, k_pad,
      Wt, D_DIM, Vb, k_pad,
      D_DIM, D_DIM + k_pad, gridM,
      out, D_DIM, v);
}